// Round 8
// baseline (1140.486 us; speedup 1.0000x reference)
//
#include <hip/hip_runtime.h>

typedef unsigned short u16;
typedef __attribute__((ext_vector_type(4))) unsigned short u16x4;
typedef __attribute__((ext_vector_type(8))) unsigned short u16x8;
typedef __attribute__((ext_vector_type(8))) __bf16 bf16x8;
typedef __attribute__((ext_vector_type(4))) float f32x4;

#define DEV __device__ __forceinline__

DEV float b2f(u16 u){ union{ unsigned int i; float f; } x; x.i = ((unsigned int)u) << 16; return x.f; }
DEV u16 f2b(float f){ unsigned int x = __float_as_uint(f); return (u16)((x + 0x7fffu + ((x >> 16) & 1u)) >> 16); }

// ---------------------------------------------------------------- block reduce (256 thr)
DEV void block_red2(float& s, float& q){
#pragma unroll
  for (int off = 32; off; off >>= 1){ s += __shfl_down(s, off); q += __shfl_down(q, off); }
  __shared__ float sh1[4], sh2[4];
  int lane = threadIdx.x & 63, w = threadIdx.x >> 6;
  if (lane == 0){ sh1[w] = s; sh2[w] = q; }
  __syncthreads();
  s = sh1[0] + sh1[1] + sh1[2] + sh1[3];
  q = sh2[0] + sh2[1] + sh2[2] + sh2[3];
}

// ---------------------------------------------------------------- GEMM  C = A[M,K] * B[N,K]^T
template<int WM, int WN, bool OUTB>
__global__ __launch_bounds__(WM*WN*64) void gemm_bt(
    const u16* __restrict__ A, const u16* __restrict__ Bm, void* __restrict__ Cp,
    int K, int lda, int ldb, int ldc, int Hh,
    long aob, long aoh, long bob, long boh, long cob, long coh)
{
  constexpr int BM = WM*64, BN = WN*64, BK = 64, LSTR = BK + 8;
  __shared__ u16 At[BM*LSTR];
  __shared__ u16 Bt[BN*LSTR];
  int z = blockIdx.z, b_ = z / Hh, h_ = z % Hh;
  const u16* Ab = A + (long)b_*aob + (long)h_*aoh;
  const u16* Bb = Bm + (long)b_*bob + (long)h_*boh;
  long cbase = (long)b_*cob + (long)h_*coh;
  int m0 = blockIdx.y * BM, n0 = blockIdx.x * BN;
  int tid = threadIdx.x, lane = tid & 63, wv = tid >> 6;
  int wm = wv / WN, wn = wv % WN;
  constexpr int T = WM*WN*64;
  f32x4 acc[4][4];
  f32x4 z4 = {0.f, 0.f, 0.f, 0.f};
#pragma unroll
  for (int a = 0; a < 4; a++)
#pragma unroll
    for (int b = 0; b < 4; b++) acc[a][b] = z4;
  int lr = lane & 15, lk8 = (lane >> 4) * 8;
  for (int k0 = 0; k0 < K; k0 += BK){
    __syncthreads();
    for (int idx = tid; idx < BM*8; idx += T){
      int r = idx >> 3, c = (idx & 7) << 3;
      *(u16x8*)&At[r*LSTR + c] = *(const u16x8*)&Ab[(long)(m0 + r)*lda + k0 + c];
    }
    for (int idx = tid; idx < BN*8; idx += T){
      int r = idx >> 3, c = (idx & 7) << 3;
      *(u16x8*)&Bt[r*LSTR + c] = *(const u16x8*)&Bb[(long)(n0 + r)*ldb + k0 + c];
    }
    __syncthreads();
#pragma unroll
    for (int kk = 0; kk < BK; kk += 32){
      bf16x8 af[4], bfr[4];
#pragma unroll
      for (int mi = 0; mi < 4; mi++) af[mi]  = *(bf16x8*)&At[(wm*64 + mi*16 + lr)*LSTR + kk + lk8];
#pragma unroll
      for (int ni = 0; ni < 4; ni++) bfr[ni] = *(bf16x8*)&Bt[(wn*64 + ni*16 + lr)*LSTR + kk + lk8];
#pragma unroll
      for (int mi = 0; mi < 4; mi++)
#pragma unroll
        for (int ni = 0; ni < 4; ni++)
          acc[mi][ni] = __builtin_amdgcn_mfma_f32_16x16x32_bf16(af[mi], bfr[ni], acc[mi][ni], 0, 0, 0);
    }
  }
  int orow = (lane >> 4) * 4, ocol = lane & 15;
#pragma unroll
  for (int mi = 0; mi < 4; mi++)
#pragma unroll
    for (int ni = 0; ni < 4; ni++){
      int row = m0 + wm*64 + mi*16 + orow;
      int col = n0 + wn*64 + ni*16 + ocol;
      long cidx = cbase + (long)row*ldc + col;
#pragma unroll
      for (int r = 0; r < 4; r++){
        float vv = acc[mi][ni][r];
        if (OUTB) ((u16*)Cp)[cidx + (long)r*ldc] = f2b(vv);
        else      ((float*)Cp)[cidx + (long)r*ldc] = vv;
      }
    }
}

// ---------------------------------------------------------------- fused attention, query-axis softmax
// Pass A v2: barrier-free. Per (b,h,j-tile of 64); wave w owns j-rows w*16..+16 (K A-frags
// in registers); Q B-frags streamed directly from global (L2-resident).
template<int KD, bool MASK>
__global__ __launch_bounds__(256) void attn_passA(
    const u16* __restrict__ Kp, const u16* __restrict__ Qp, float* __restrict__ mz,
    int J, int kld, int qld,
    long kob, long koh, long qob, long qoh, int H, float scale, int mztot)
{
  constexpr int NC = KD / 32;
  int bh = blockIdx.y, b = bh / H, h = bh % H;
  const u16* Kb = Kp + (long)b*kob + (long)h*koh;
  const u16* Qb = Qp + (long)b*qob + (long)h*qoh;
  int j0 = blockIdx.x * 64;
  int tid = threadIdx.x, lane = tid & 63, w = tid >> 6;
  int lr = lane & 15, lk8 = (lane >> 4) * 8;
  bf16x8 ak[NC];
  long jrow = j0 + w*16 + lr;
#pragma unroll
  for (int c = 0; c < NC; c++) ak[c] = *(const bf16x8*)&Kb[jrow*kld + c*32 + lk8];
  float m_run[4], z_run[4];
#pragma unroll
  for (int r = 0; r < 4; r++){ m_run[r] = -3.0e38f; z_run[r] = 0.f; }
  f32x4 zz = {0.f,0.f,0.f,0.f};
  for (int it = 0; it < 8; it++){
    if (MASK && (it*128 + 127 < j0 - 1024)) continue;   // i-tile fully masked (uniform)
    f32x4 acc[8];
#pragma unroll
    for (int ni = 0; ni < 8; ni++) acc[ni] = zz;
#pragma unroll
    for (int c = 0; c < NC; c++){
      bf16x8 bq[8];
#pragma unroll
      for (int ni = 0; ni < 8; ni++)
        bq[ni] = *(const bf16x8*)&Qb[(long)(it*128 + ni*16 + lr)*qld + c*32 + lk8];
#pragma unroll
      for (int ni = 0; ni < 8; ni++)
        acc[ni] = __builtin_amdgcn_mfma_f32_16x16x32_bf16(ak[c], bq[ni], acc[ni], 0, 0, 0);
    }
#pragma unroll
    for (int r = 0; r < 4; r++){
      int jg = j0 + w*16 + ((lane >> 4) << 2) + r;
      float sv[8]; float tm = -3.0e38f;
#pragma unroll
      for (int ni = 0; ni < 8; ni++){
        int ig = it*128 + ni*16 + (lane & 15);
        float s = acc[ni][r] * scale;
        bool val = (!MASK) || (ig >= jg - 1024);
        sv[ni] = val ? s : -3.0e38f;
        tm = fmaxf(tm, sv[ni]);
      }
#pragma unroll
      for (int off = 1; off < 16; off <<= 1) tm = fmaxf(tm, __shfl_xor(tm, off));
      float mn = fmaxf(m_run[r], tm);
      float zt = 0.f;
#pragma unroll
      for (int ni = 0; ni < 8; ni++)
        zt += (sv[ni] > -1.0e37f) ? __expf(sv[ni] - mn) : 0.f;
#pragma unroll
      for (int off = 1; off < 16; off <<= 1) zt += __shfl_xor(zt, off);
      z_run[r] = z_run[r] * __expf(m_run[r] - mn) + zt;
      m_run[r] = mn;
    }
  }
  if ((lane & 15) == 0){
#pragma unroll
    for (int r = 0; r < 4; r++){
      int jg = j0 + w*16 + ((lane >> 4) << 2) + r;
      mz[(long)bh*J + jg] = m_run[r];
      mz[(long)mztot + (long)bh*J + jg] = 1.f / z_run[r];
    }
  }
}

// Pass B v2: barrier-free. Per (b,h,i-tile of 64); wave w owns i-rows w*16..+16 (Q A-frags
// in registers); K/V streamed from global; P transposed through a PER-WAVE LDS tile
// (C-layout -> A-layout, same-wave dep only -> lgkmcnt, no __syncthreads).
template<int KD, bool MASK>
__global__ __launch_bounds__(256) void attn_passB(
    const u16* __restrict__ Kp, const u16* __restrict__ Qp, const u16* __restrict__ Vtp,
    const float* __restrict__ mz, u16* __restrict__ Op,
    int J, int kld, int qld, int vld, int oldd,
    long kob, long koh, long qob, long qoh, long vob, long voh, long oob, long ooh,
    int H, float scale, int mztot)
{
  constexpr int NC = KD / 32, PSTR = 140;
  __shared__ u16 Pt[4][16*PSTR];                 // per-wave private P tile
  int bh = blockIdx.y, b = bh / H, h = bh % H;
  const u16* Kb = Kp + (long)b*kob + (long)h*koh;
  const u16* Qb = Qp + (long)b*qob + (long)h*qoh;
  const u16* Vb = Vtp + (long)b*vob + (long)h*voh;
  u16* Ob = Op + (long)b*oob + (long)h*ooh;
  const float* mzm = mz + (long)bh*J;
  const float* mzz = mz + (long)mztot + (long)bh*J;
  int i0 = blockIdx.x * 64;
  int tid = threadIdx.x, lane = tid & 63, w = tid >> 6;
  int lr = lane & 15, lk8 = (lane >> 4) * 8;
  u16* Pw = Pt[w];
  bf16x8 aq[NC];
  long irow = i0 + w*16 + lr;
#pragma unroll
  for (int c = 0; c < NC; c++) aq[c] = *(const bf16x8*)&Qb[irow*qld + c*32 + lk8];
  f32x4 acc_o[4];
  f32x4 zz = {0.f,0.f,0.f,0.f};
#pragma unroll
  for (int nd = 0; nd < 4; nd++) acc_o[nd] = zz;
  int JT = J >> 7;
  for (int jt = 0; jt < JT; jt++){
    if (MASK && (jt*128 > i0 + 1087)) continue;  // j-tile fully masked (uniform)
    // S tile: A = Q regs (16 i-rows), B = K direct-global (128 j)
    f32x4 acc[8];
#pragma unroll
    for (int ni = 0; ni < 8; ni++) acc[ni] = zz;
#pragma unroll
    for (int c = 0; c < NC; c++){
      bf16x8 bk[8];
#pragma unroll
      for (int ni = 0; ni < 8; ni++)
        bk[ni] = *(const bf16x8*)&Kb[(long)(jt*128 + ni*16 + lr)*kld + c*32 + lk8];
#pragma unroll
      for (int ni = 0; ni < 8; ni++)
        acc[ni] = __builtin_amdgcn_mfma_f32_16x16x32_bf16(aq[c], bk[ni], acc[ni], 0, 0, 0);
    }
    // p = exp(s*scale - m_j) * zinv_j  (masked -> 0); write C-layout into per-wave P
#pragma unroll
    for (int ni = 0; ni < 8; ni++){
      int jg = jt*128 + ni*16 + (lane & 15);
      float mj = mzm[jg], zj = mzz[jg];
#pragma unroll
      for (int r = 0; r < 4; r++){
        int ig = i0 + w*16 + ((lane >> 4) << 2) + r;
        bool val = (!MASK) || (ig >= jg - 1024);
        float p = val ? __expf(acc[ni][r] * scale - mj) * zj : 0.f;
        Pw[(((lane >> 4) << 2) + r)*PSTR + ni*16 + (lane & 15)] = f2b(p);
      }
    }
    // PV: A = P (A-layout read, same wave), B = Vt direct-global (64 d-rows)
#pragma unroll
    for (int c2 = 0; c2 < 4; c2++){
      bf16x8 pa = *(bf16x8*)&Pw[lr*PSTR + c2*32 + lk8];
      bf16x8 vb[4];
#pragma unroll
      for (int nd = 0; nd < 4; nd++)
        vb[nd] = *(const bf16x8*)&Vb[(long)(nd*16 + lr)*vld + jt*128 + c2*32 + lk8];
#pragma unroll
      for (int nd = 0; nd < 4; nd++)
        acc_o[nd] = __builtin_amdgcn_mfma_f32_16x16x32_bf16(pa, vb[nd], acc_o[nd], 0, 0, 0);
    }
  }
#pragma unroll
  for (int nd = 0; nd < 4; nd++)
#pragma unroll
    for (int r = 0; r < 4; r++){
      int ig = i0 + w*16 + ((lane >> 4) << 2) + r;
      int d = nd*16 + (lane & 15);
      Ob[(long)ig*oldd + d] = f2b(acc_o[nd][r]);
    }
}

// ---------------------------------------------------------------- bf16 transpose dst[c,r]=src[r,c]
__global__ __launch_bounds__(256) void transpose_k(
    const u16* __restrict__ src, u16* __restrict__ dst,
    int lds_, int ldd, int Hh, long sob, long soh, long dob, long doh)
{
  __shared__ u16 tile[64*72];
  int z = blockIdx.z, b_ = z / Hh, h_ = z % Hh;
  const u16* S_ = src + (long)b_*sob + (long)h_*soh;
  u16* D_ = dst + (long)b_*dob + (long)h_*doh;
  int r0 = blockIdx.y * 64, c0 = blockIdx.x * 64;
  int tid = threadIdx.x;
  for (int idx = tid; idx < 512; idx += 256){
    int r = idx >> 3, c = (idx & 7) << 3;
    *(u16x8*)&tile[r*72 + c] = *(const u16x8*)&S_[(long)(r0 + r)*lds_ + c0 + c];
  }
  __syncthreads();
  for (int idx = tid; idx < 512; idx += 256){
    int c = idx >> 3, r = (idx & 7) << 3;
    u16x8 v;
#pragma unroll
    for (int e = 0; e < 8; e++) v[e] = tile[(r + e)*72 + c];
    *(u16x8*)&D_[(long)(c0 + c)*ldd + r0 + r] = v;
  }
}

// ---------------------------------------------------------------- fp32 src -> bf16 transposed dst
__global__ __launch_bounds__(256) void transpose_cvt_k(
    const float* __restrict__ src, u16* __restrict__ dst, int lds_, int ldd)
{
  __shared__ u16 tile[64*72];
  int r0 = blockIdx.y * 64, c0 = blockIdx.x * 64;
  int tid = threadIdx.x;
  for (int idx = tid; idx < 512; idx += 256){
    int r = idx >> 3, c = (idx & 7) << 3;
    const float* s = &src[(long)(r0 + r)*lds_ + c0 + c];
#pragma unroll
    for (int e = 0; e < 8; e++) tile[r*72 + c + e] = f2b(s[e]);
  }
  __syncthreads();
  for (int idx = tid; idx < 512; idx += 256){
    int c = idx >> 3, r = (idx & 7) << 3;
    u16x8 v;
#pragma unroll
    for (int e = 0; e < 8; e++) v[e] = tile[(r + e)*72 + c];
    *(u16x8*)&dst[(long)(c0 + c)*ldd + r0 + r] = v;
  }
}

// ---------------------------------------------------------------- flat fp32 -> bf16
__global__ __launch_bounds__(256) void cvt_k(const float* __restrict__ src, u16* __restrict__ dst)
{
  long i = ((long)blockIdx.x*256 + threadIdx.x) * 4;
  float4 v = *(const float4*)&src[i];
  u16x4 o; o[0] = f2b(v.x); o[1] = f2b(v.y); o[2] = f2b(v.z); o[3] = f2b(v.w);
  *(u16x4*)&dst[i] = o;
}

// ---------------------------------------------------------------- LayerNorm row=1024, fp32 in, bf16 out
__global__ __launch_bounds__(256) void ln_k(const float* __restrict__ src, const float* __restrict__ g,
                                            const float* __restrict__ be, u16* __restrict__ out)
{
  long base = (long)blockIdx.x * 1024;
  int tid = threadIdx.x;
  const float* s = src + base + tid*4;
  float v[4] = {s[0], s[1], s[2], s[3]};
  float s1 = v[0]+v[1]+v[2]+v[3];
  float s2 = v[0]*v[0]+v[1]*v[1]+v[2]*v[2]+v[3]*v[3];
  block_red2(s1, s2);
  float mu = s1 * (1.f/1024.f);
  float var = s2 * (1.f/1024.f) - mu*mu;
  float rs = rsqrtf(var + 1e-5f);
#pragma unroll
  for (int e = 0; e < 4; e++){
    int col = tid*4 + e;
    out[base + col] = f2b((v[e]-mu)*rs*g[col] + be[col]);
  }
}

// ---------------------------------------------------------------- out = resid + LN(sum4(go) + xn + bias)  (fp32 out)
__global__ __launch_bounds__(256) void add_ln_k(const float* __restrict__ go,
    const u16* __restrict__ xn, const float* __restrict__ bias,
    const float* __restrict__ g, const float* __restrict__ be,
    const float* __restrict__ resid, float* __restrict__ outp)
{
  const long PS = 2097152;
  long base = (long)blockIdx.x * 1024;
  int tid = threadIdx.x;
  float v[4];
#pragma unroll
  for (int e = 0; e < 4; e++){
    int col = tid*4 + e;
    long idx = base + col;
    v[e] = go[idx] + go[idx + PS] + go[idx + 2*PS] + go[idx + 3*PS] + b2f(xn[idx]) + bias[col];
  }
  float s1 = v[0]+v[1]+v[2]+v[3];
  float s2 = v[0]*v[0]+v[1]*v[1]+v[2]*v[2]+v[3]*v[3];
  block_red2(s1, s2);
  float mu = s1 * (1.f/1024.f);
  float var = s2 * (1.f/1024.f) - mu*mu;
  float rs = rsqrtf(var + 1e-5f);
#pragma unroll
  for (int e = 0; e < 4; e++){
    int col = tid*4 + e;
    outp[base + col] = resid[base + col] + (v[e]-mu)*rs*g[col] + be[col];
  }
}

// ---------------------------------------------------------------- QQ = [q+u | shifted(q+v)]  (B,S,H,128)
__global__ __launch_bounds__(256) void build_qq(const u16* __restrict__ q, const float* __restrict__ u,
                                                const float* __restrict__ v, u16* __restrict__ QQ)
{
  int bi = blockIdx.x;
  long qrow = (long)bi * 1024;
  long obase = (long)bi * 2048;
  int n = bi + 2;
  int bp = n / 1025, ip = n % 1025;
  long qsrc = ip ? ((long)(bp*1024 + ip - 1)) * 1024 : -1;
  for (int t = threadIdx.x; t < 2048; t += 256){
    int h = t >> 7, e = t & 127;
    float val;
    if (e < 64) val = b2f(q[qrow + h*64 + e]) + u[h*64 + e];
    else {
      int d = e - 64;
      val = (qsrc < 0) ? 0.f : b2f(q[qsrc + h*64 + d]) + v[h*64 + d];
    }
    QQ[obase + t] = f2b(val);
  }
}

// ---------------------------------------------------------------- BB = [k | pos_emb]  (B,St,H,128)
__global__ __launch_bounds__(256) void build_bb(const u16* __restrict__ kv, const float* __restrict__ pe,
                                                u16* __restrict__ BB)
{
  int bj = blockIdx.x;
  int j = bj & 2047;
  long kvrow = (long)bj * 2048;
  long obase = (long)bj * 2048;
  for (int t = threadIdx.x; t < 2048; t += 256){
    int h = t >> 7, e = t & 127;
    u16 val = (e < 64) ? kv[kvrow + h*64 + e] : f2b(pe[(long)j*1024 + h*64 + (e - 64)]);
    BB[obase + t] = val;
  }
}

// ---------------------------------------------------------------- gelu(exact) + bias, fp32 in, bf16 out
__global__ __launch_bounds__(256) void gelu_k(const float* __restrict__ f1, const float* __restrict__ b1,
                                              u16* __restrict__ h1)
{
  long i = (long)blockIdx.x*256 + threadIdx.x;
  float x = f1[i] + b1[i & 4095];
  h1[i] = f2b(0.5f * x * (1.f + erff(x * 0.70710678118654752f)));
}

// ---------------------------------------------------------------- out3 = out2 + sum4(f2) + b2  (fp32 out)
__global__ __launch_bounds__(256) void final_k(const float* __restrict__ out2, const float* __restrict__ f2,
                                               const float* __restrict__ b2v, float* __restrict__ outp)
{
  const long PS = 2097152;
  long i = (long)blockIdx.x*256 + threadIdx.x;
  outp[i] = out2[i] + f2[i] + f2[i + PS] + f2[i + 2*PS] + f2[i + 3*PS] + b2v[i & 1023];
}

// ================================================================ host
extern "C" void kernel_launch(void* const* d_in, const int* in_sizes, int n_in,
                              void* d_out, int out_size, void* d_ws, size_t ws_size,
                              hipStream_t stream)
{
  (void)in_sizes; (void)n_in; (void)out_size; (void)ws_size;
  // B=2 S=1024 M=1024 St=2048 D=DI=1024 H=16 DH=64 DFF=4096 ; ALL inputs/output fp32
  const float* X    = (const float*)d_in[0];
  const float* ENC  = (const float*)d_in[1];
  const float* PE   = (const float*)d_in[2];
  const float* Uu   = (const float*)d_in[3];
  const float* Vv   = (const float*)d_in[4];
  const float* MEM  = (const float*)d_in[5];
  const float* WQM  = (const float*)d_in[7];
  const float* WKVM = (const float*)d_in[8];
  const float* FCWM = (const float*)d_in[9];
  const float* FCBM = (const float*)d_in[10];
  const float* LNMG = (const float*)d_in[11];
  const float* LNMB = (const float*)d_in[12];
  const float* WQC  = (const float*)d_in[13];
  const float* WKVC = (const float*)d_in[14];
  const float* FCWC = (const float*)d_in[15];
  const float* FCBC = (const float*)d_in[16];
  const float* LNCG = (const float*)d_in[17];
  const float* LNCB = (const float*)d_in[18];
  const float* W1   = (const float*)d_in[19];
  const float* B1   = (const float*)d_in[20];
  const float* W2   = (const float*)d_in[21];
  const float* B2   = (const float*)d_in[22];
  const float* LN1G = (const float*)d_in[23];
  const float* LN1B = (const float*)d_in[24];
  const float* LN2G = (const float*)d_in[25];
  const float* LN2B = (const float*)d_in[26];
  const float* LN3G = (const float*)d_in[27];
  const float* LN3B = (const float*)d_in[28];
  float* OUT = (float*)d_out;
  char* W = (char*)d_ws;
  const size_t MB = 1ull << 20;

  // ---- layout, peak 122 MB (same as R7)
  u16*   wT_a  = (u16*)(W + 0*MB);
  u16*   wT_b  = (u16*)(W + 2*MB);
  u16*   wT_c  = (u16*)(W + 6*MB);
  u16*   w1T   = (u16*)(W + 0*MB);
  u16*   xn1   = (u16*)(W + 8*MB);
  u16*   q     = (u16*)(W + 12*MB);
  u16*   o_b   = (u16*)(W + 12*MB);
  u16*   kv    = (u16*)(W + 16*MB);
  float* outb  = (float*)(W + 24*MB);
  u16*   QQ    = (u16*)(W + 32*MB);
  u16*   xn2   = (u16*)(W + 32*MB);
  u16*   qc    = (u16*)(W + 36*MB);
  u16*   BB    = (u16*)(W + 40*MB);
  u16*   kvc   = (u16*)(W + 40*MB);
  u16*   Vtc   = (u16*)(W + 48*MB);
  u16*   oc    = (u16*)(W + 52*MB);
  u16*   Vt    = (u16*)(W + 56*MB);
  u16*   w2T   = (u16*)(W + 56*MB);
  float* mzb   = (float*)(W + 64*MB);
  u16*   memb  = (u16*)(W + 68*MB);
  u16*   encb  = (u16*)(W + 68*MB);
  float* ofc   = (float*)(W + 66*MB);    // 4 partials x 8 MB
  float* f1    = (float*)(W + 66*MB);
  float* f2    = (float*)(W + 66*MB);    // 4 partials x 8 MB
  u16*   h1    = (u16*)(W + 98*MB);
  float* out2b = (float*)(W + 114*MB);

  // ================= MHA (Transformer-XL relative attention) =================
  transpose_cvt_k<<<dim3(16,16),256,0,stream>>>(WQM,  wT_a, 1024,1024);
  transpose_cvt_k<<<dim3(32,16),256,0,stream>>>(WKVM, wT_b, 2048,1024);
  transpose_cvt_k<<<dim3(16,16),256,0,stream>>>(FCWM, wT_c, 1024,1024);
  cvt_k<<<2048,256,0,stream>>>(MEM, memb);
  ln_k<<<2048,256,0,stream>>>(X, LN1G, LN1B, xn1);
  gemm_bt<2,2,true><<<dim3(8,16,1),256,0,stream>>>(xn1, wT_a, q, 1024, 1024,1024,1024, 1, 0,0,0,0,0,0);
  gemm_bt<2,2,true><<<dim3(16,8,2),256,0,stream>>>(memb, wT_b, kv, 1024, 1024,1024,2048, 1,
      1048576,0, 0,0, 4194304,0);
  gemm_bt<2,2,true><<<dim3(16,8,2),256,0,stream>>>(xn1, wT_b, kv + (size_t)1024*2048, 1024, 1024,1024,2048, 1,
      1048576,0, 0,0, 4194304,0);
  build_qq<<<2048,256,0,stream>>>(q, Uu, Vv, QQ);
  build_bb<<<4096,256,0,stream>>>(kv, PE, BB);
  transpose_k<<<dim3(1,32,32),256,0,stream>>>(kv + 1024, Vt, 2048, 2048, 16,
      4194304,64, 2097152,131072);
  attn_passA<128,true><<<dim3(32,32),256,0,stream>>>(BB, QQ, mzb, 2048, 2048, 2048,
      4194304,128, 2097152,128, 16, 0.125f, 65536);
  attn_passB<128,true><<<dim3(16,32),256,0,stream>>>(BB, QQ, Vt, mzb, o_b, 2048,
      2048,2048,2048,1024, 4194304,128, 2097152,128, 2097152,131072, 1048576,64, 16, 0.125f, 65536);
  gemm_bt<2,2,false><<<dim3(8,16,4),256,0,stream>>>(o_b, wT_c, ofc, 256, 1024,1024,1024, 4,
      0,256, 0,256, 0,2097152);
  add_ln_k<<<2048,256,0,stream>>>(ofc, xn1, FCBM, LNMG, LNMB, X, outb);

  // ================= cross attention =================
  transpose_cvt_k<<<dim3(16,16),256,0,stream>>>(WQC,  wT_a, 1024,1024);
  transpose_cvt_k<<<dim3(32,16),256,0,stream>>>(WKVC, wT_b, 2048,1024);
  transpose_cvt_k<<<dim3(16,16),256,0,stream>>>(FCWC, wT_c, 1024,1024);
  cvt_k<<<2048,256,0,stream>>>(ENC, encb);
  ln_k<<<2048,256,0,stream>>>(outb, LN2G, LN2B, xn2);
  gemm_bt<2,2,true><<<dim3(8,16,1),256,0,stream>>>(xn2, wT_a, qc, 1024, 1024,1024,1024, 1, 0,0,0,0,0,0);
  gemm_bt<2,2,true><<<dim3(16,16,1),256,0,stream>>>(encb, wT_b, kvc, 1024, 1024,1024,2048, 1, 0,0,0,0,0,0);
  transpose_k<<<dim3(1,16,32),256,0,stream>>>(kvc + 1024, Vtc, 2048, 1024, 16,
      2097152,64, 1048576,65536);
  attn_passA<64,false><<<dim3(16,32),256,0,stream>>>(kvc, qc, mzb, 1024, 2048, 1024,
      2097152,64, 1048576,64, 16, 0.125f, 32768);
  attn_passB<64,false><<<dim3(16,32),256,0,stream>>>(kvc, qc, Vtc, mzb, oc, 1024,
      2048,1024,1024,1024, 2097152,64, 1048576,64, 1048576,65536, 1048576,64, 16, 0.125f, 32768);
  gemm_bt<2,2,false><<<dim3(8,16,4),256,0,stream>>>(oc, wT_c, ofc, 256, 1024,1024,1024, 4,
      0,256, 0,256, 0,2097152);
  add_ln_k<<<2048,256,0,stream>>>(ofc, xn2, FCBC, LNCG, LNCB, outb, out2b);

  // ================= FFN =================
  transpose_cvt_k<<<dim3(64,16),256,0,stream>>>(W1, w1T, 4096,1024);
  transpose_cvt_k<<<dim3(16,64),256,0,stream>>>(W2, w2T, 1024,4096);
  ln_k<<<2048,256,0,stream>>>(out2b, LN3G, LN3B, xn2);
  gemm_bt<2,2,false><<<dim3(32,16,1),256,0,stream>>>(xn2, w1T, f1, 1024, 1024,1024,4096, 1, 0,0,0,0,0,0);
  gelu_k<<<32768,256,0,stream>>>(f1, B1, h1);
  gemm_bt<2,2,false><<<dim3(8,16,4),256,0,stream>>>(h1, w2T, f2, 1024, 4096,4096,1024, 4,
      0,1024, 0,1024, 0,2097152);
  final_k<<<8192,256,0,stream>>>(out2b, f2, B2, OUT);
}

// Round 9
// 768.546 us; speedup vs baseline: 1.4840x; 1.4840x over previous
//
#include <hip/hip_runtime.h>

typedef unsigned short u16;
typedef __attribute__((ext_vector_type(4))) unsigned short u16x4;
typedef __attribute__((ext_vector_type(8))) unsigned short u16x8;
typedef __attribute__((ext_vector_type(8))) __bf16 bf16x8;
typedef __attribute__((ext_vector_type(4))) float f32x4;

#define DEV __device__ __forceinline__

DEV float b2f(u16 u){ union{ unsigned int i; float f; } x; x.i = ((unsigned int)u) << 16; return x.f; }
DEV u16 f2b(float f){ unsigned int x = __float_as_uint(f); return (u16)((x + 0x7fffu + ((x >> 16) & 1u)) >> 16); }

// ---------------------------------------------------------------- block reduce (256 thr)
DEV void block_red2(float& s, float& q){
#pragma unroll
  for (int off = 32; off; off >>= 1){ s += __shfl_down(s, off); q += __shfl_down(q, off); }
  __shared__ float sh1[4], sh2[4];
  int lane = threadIdx.x & 63, w = threadIdx.x >> 6;
  if (lane == 0){ sh1[w] = s; sh2[w] = q; }
  __syncthreads();
  s = sh1[0] + sh1[1] + sh1[2] + sh1[3];
  q = sh2[0] + sh2[1] + sh2[2] + sh2[3];
}

// ---------------------------------------------------------------- GEMM  C = A[M,K] * B[N,K]^T
// m97 recipe: async global->LDS (width 16), unpadded lane-contiguous LDS tiles.
template<int WM, int WN, bool OUTB>
__global__ __launch_bounds__(WM*WN*64) void gemm_bt(
    const u16* __restrict__ A, const u16* __restrict__ Bm, void* __restrict__ Cp,
    int K, int lda, int ldb, int ldc, int Hh,
    long aob, long aoh, long bob, long boh, long cob, long coh)
{
  constexpr int BM = WM*64, BN = WN*64, BK = 64, NW = WM*WN;
  __shared__ u16 At[BM*64];
  __shared__ u16 Bt[BN*64];
  int z = blockIdx.z, b_ = z / Hh, h_ = z % Hh;
  const u16* Ab = A + (long)b_*aob + (long)h_*aoh;
  const u16* Bb = Bm + (long)b_*bob + (long)h_*boh;
  long cbase = (long)b_*cob + (long)h_*coh;
  int m0 = blockIdx.y * BM, n0 = blockIdx.x * BN;
  int tid = threadIdx.x, lane = tid & 63, wv = tid >> 6;
  int wm = wv / WN, wn = wv % WN;
  f32x4 acc[4][4];
  f32x4 z4 = {0.f, 0.f, 0.f, 0.f};
#pragma unroll
  for (int a = 0; a < 4; a++)
#pragma unroll
    for (int b = 0; b < 4; b++) acc[a][b] = z4;
  int lr = lane & 15, lk8 = (lane >> 4) * 8;
  int rq = lane >> 3, cq = (lane & 7) << 3;      // lane -> (row-in-8, col-16B) of one inst
  for (int k0 = 0; k0 < K; k0 += BK){
    __syncthreads();                             // prev MFMA reads done before overwrite
#pragma unroll
    for (int q = wv; q < BM/8; q += NW){
      const u16* g = &Ab[(long)(m0 + q*8 + rq)*lda + k0 + cq];
      __builtin_amdgcn_global_load_lds((const __attribute__((address_space(1))) void*)g,
          (__attribute__((address_space(3))) void*)&At[q*512], 16, 0, 0);
    }
#pragma unroll
    for (int q = wv; q < BN/8; q += NW){
      const u16* g = &Bb[(long)(n0 + q*8 + rq)*ldb + k0 + cq];
      __builtin_amdgcn_global_load_lds((const __attribute__((address_space(1))) void*)g,
          (__attribute__((address_space(3))) void*)&Bt[q*512], 16, 0, 0);
    }
    __syncthreads();                             // drains vmcnt (loads landed in LDS)
#pragma unroll
    for (int kk = 0; kk < BK; kk += 32){
      bf16x8 af[4], bfr[4];
#pragma unroll
      for (int mi = 0; mi < 4; mi++) af[mi]  = *(bf16x8*)&At[(wm*64 + mi*16 + lr)*64 + kk + lk8];
#pragma unroll
      for (int ni = 0; ni < 4; ni++) bfr[ni] = *(bf16x8*)&Bt[(wn*64 + ni*16 + lr)*64 + kk + lk8];
#pragma unroll
      for (int mi = 0; mi < 4; mi++)
#pragma unroll
        for (int ni = 0; ni < 4; ni++)
          acc[mi][ni] = __builtin_amdgcn_mfma_f32_16x16x32_bf16(af[mi], bfr[ni], acc[mi][ni], 0, 0, 0);
    }
  }
  int orow = (lane >> 4) * 4, ocol = lane & 15;
#pragma unroll
  for (int mi = 0; mi < 4; mi++)
#pragma unroll
    for (int ni = 0; ni < 4; ni++){
      int row = m0 + wm*64 + mi*16 + orow;
      int col = n0 + wn*64 + ni*16 + ocol;
      long cidx = cbase + (long)row*ldc + col;
#pragma unroll
      for (int r = 0; r < 4; r++){
        float vv = acc[mi][ni][r];
        if (OUTB) ((u16*)Cp)[cidx + (long)r*ldc] = f2b(vv);
        else      ((float*)Cp)[cidx + (long)r*ldc] = vv;
      }
    }
}

// ---------------------------------------------------------------- fused attention (R7 proven version)
// Pass A: per (b,h,j-tile of 64): m_j, 1/Z_j over all i (masked). 4 waves x 16 j-rows.
template<int KD, bool MASK>
__global__ __launch_bounds__(256) void attn_passA(
    const u16* __restrict__ Kp, const u16* __restrict__ Qp, float* __restrict__ mz,
    int J, int kld, int qld,
    long kob, long koh, long qob, long qoh, int H, float scale, int mztot)
{
  constexpr int KP = KD + 8;
  __shared__ u16 Kt[64*KP];
  __shared__ u16 Qt[128*KP];
  int bh = blockIdx.y, b = bh / H, h = bh % H;
  const u16* Kb = Kp + (long)b*kob + (long)h*koh;
  const u16* Qb = Qp + (long)b*qob + (long)h*qoh;
  int j0 = blockIdx.x * 64;
  int tid = threadIdx.x, lane = tid & 63, w = tid >> 6;
  int lr = lane & 15, lk8 = (lane >> 4) * 8;
  constexpr int RCH = KD / 8;
  for (int idx = tid; idx < 64*RCH; idx += 256){
    int r = idx / RCH, c = (idx % RCH) * 8;
    *(u16x8*)&Kt[r*KP + c] = *(const u16x8*)&Kb[(long)(j0 + r)*kld + c];
  }
  float m_run[4], z_run[4];
#pragma unroll
  for (int r = 0; r < 4; r++){ m_run[r] = -3.0e38f; z_run[r] = 0.f; }
  f32x4 zz = {0.f,0.f,0.f,0.f};
  for (int it = 0; it < 8; it++){
    if (MASK && (it*128 + 127 < j0 - 1024)) continue;   // i-tile fully masked (uniform)
    __syncthreads();
    for (int idx = tid; idx < 128*RCH; idx += 256){
      int r = idx / RCH, c = (idx % RCH) * 8;
      *(u16x8*)&Qt[r*KP + c] = *(const u16x8*)&Qb[(long)(it*128 + r)*qld + c];
    }
    __syncthreads();
    f32x4 acc[8];
#pragma unroll
    for (int ni = 0; ni < 8; ni++) acc[ni] = zz;
#pragma unroll
    for (int kk = 0; kk < KD; kk += 32){
      bf16x8 af, bq[8];
      af = *(bf16x8*)&Kt[(w*16 + lr)*KP + kk + lk8];
#pragma unroll
      for (int ni = 0; ni < 8; ni++) bq[ni] = *(bf16x8*)&Qt[(ni*16 + lr)*KP + kk + lk8];
#pragma unroll
      for (int ni = 0; ni < 8; ni++)
        acc[ni] = __builtin_amdgcn_mfma_f32_16x16x32_bf16(af, bq[ni], acc[ni], 0, 0, 0);
    }
#pragma unroll
    for (int r = 0; r < 4; r++){
      int jg = j0 + w*16 + ((lane >> 4) << 2) + r;
      float sv[8]; float tm = -3.0e38f;
#pragma unroll
      for (int ni = 0; ni < 8; ni++){
        int ig = it*128 + ni*16 + (lane & 15);
        float s = acc[ni][r] * scale;
        bool val = (!MASK) || (ig >= jg - 1024);
        sv[ni] = val ? s : -3.0e38f;
        tm = fmaxf(tm, sv[ni]);
      }
#pragma unroll
      for (int off = 1; off < 16; off <<= 1) tm = fmaxf(tm, __shfl_xor(tm, off));
      float mn = fmaxf(m_run[r], tm);
      float zt = 0.f;
#pragma unroll
      for (int ni = 0; ni < 8; ni++)
        zt += (sv[ni] > -1.0e37f) ? __expf(sv[ni] - mn) : 0.f;
#pragma unroll
      for (int off = 1; off < 16; off <<= 1) zt += __shfl_xor(zt, off);
      z_run[r] = z_run[r] * __expf(m_run[r] - mn) + zt;
      m_run[r] = mn;
    }
  }
  if ((lane & 15) == 0){
#pragma unroll
    for (int r = 0; r < 4; r++){
      int jg = j0 + w*16 + ((lane >> 4) << 2) + r;
      mz[(long)bh*J + jg] = m_run[r];
      mz[(long)mztot + (long)bh*J + jg] = 1.f / z_run[r];
    }
  }
}

// Pass B: per (b,h,i-tile of 64). LDS-staged K/V (block reuse), padded strides.
template<int KD, bool MASK>
__global__ __launch_bounds__(256) void attn_passB(
    const u16* __restrict__ Kp, const u16* __restrict__ Qp, const u16* __restrict__ Vtp,
    const float* __restrict__ mz, u16* __restrict__ Op,
    int J, int kld, int qld, int vld, int oldd,
    long kob, long koh, long qob, long qoh, long vob, long voh, long oob, long ooh,
    int H, float scale, int mztot)
{
  constexpr int KP = KD + 8, PSTR = 140, VSTR = 136;
  __shared__ u16 Qt[64*KP];
  __shared__ u16 PK[128*KP];       // K tile (128 x KP) ; aliased by P tile (64 x PSTR)
  __shared__ u16 Vtt[64*VSTR];
  u16* Kt = PK;
  u16* Pt = PK;
  int bh = blockIdx.y, b = bh / H, h = bh % H;
  const u16* Kb = Kp + (long)b*kob + (long)h*koh;
  const u16* Qb = Qp + (long)b*qob + (long)h*qoh;
  const u16* Vb = Vtp + (long)b*vob + (long)h*voh;
  u16* Ob = Op + (long)b*oob + (long)h*ooh;
  const float* mzm = mz + (long)bh*J;
  const float* mzz = mz + (long)mztot + (long)bh*J;
  int i0 = blockIdx.x * 64;
  int tid = threadIdx.x, lane = tid & 63, w = tid >> 6;
  int lr = lane & 15, lk8 = (lane >> 4) * 8;
  constexpr int RCH = KD / 8;
  for (int idx = tid; idx < 64*RCH; idx += 256){
    int r = idx / RCH, c = (idx % RCH) * 8;
    *(u16x8*)&Qt[r*KP + c] = *(const u16x8*)&Qb[(long)(i0 + r)*qld + c];
  }
  f32x4 acc_o[4];
  f32x4 zz = {0.f,0.f,0.f,0.f};
#pragma unroll
  for (int nd = 0; nd < 4; nd++) acc_o[nd] = zz;
  int JT = J >> 7;
  for (int jt = 0; jt < JT; jt++){
    if (MASK && (jt*128 > i0 + 1087)) continue;    // j-tile fully masked (uniform)
    __syncthreads();                               // prior P/Vt reads done before restage
    for (int idx = tid; idx < 128*RCH; idx += 256){
      int r = idx / RCH, c = (idx % RCH) * 8;
      *(u16x8*)&Kt[r*KP + c] = *(const u16x8*)&Kb[(long)(jt*128 + r)*kld + c];
    }
    for (int idx = tid; idx < 64*16; idx += 256){
      int r = idx >> 4, c = (idx & 15) << 3;
      *(u16x8*)&Vtt[r*VSTR + c] = *(const u16x8*)&Vb[(long)r*vld + jt*128 + c];
    }
    __syncthreads();
    // S tile: A = Q (own wave's 16 i-rows), B = K (128 j)
    f32x4 acc[8];
#pragma unroll
    for (int ni = 0; ni < 8; ni++) acc[ni] = zz;
#pragma unroll
    for (int kk = 0; kk < KD; kk += 32){
      bf16x8 aq, bk[8];
      aq = *(bf16x8*)&Qt[(w*16 + lr)*KP + kk + lk8];
#pragma unroll
      for (int ni = 0; ni < 8; ni++) bk[ni] = *(bf16x8*)&Kt[(ni*16 + lr)*KP + kk + lk8];
#pragma unroll
      for (int ni = 0; ni < 8; ni++)
        acc[ni] = __builtin_amdgcn_mfma_f32_16x16x32_bf16(aq, bk[ni], acc[ni], 0, 0, 0);
    }
    __syncthreads();                               // K reads done before P overwrite (alias)
#pragma unroll
    for (int ni = 0; ni < 8; ni++){
      int jg = jt*128 + ni*16 + (lane & 15);
      float mj = mzm[jg], zj = mzz[jg];
#pragma unroll
      for (int r = 0; r < 4; r++){
        int ig = i0 + w*16 + ((lane >> 4) << 2) + r;
        bool val = (!MASK) || (ig >= jg - 1024);
        float p = val ? __expf(acc[ni][r] * scale - mj) * zj : 0.f;
        Pt[(w*16 + ((lane >> 4) << 2) + r)*PSTR + ni*16 + (lane & 15)] = f2b(p);
      }
    }
    __syncthreads();
    // PV: A = P (own wave's 16 i-rows), B = Vt (64 d-rows)
#pragma unroll
    for (int kk = 0; kk < 128; kk += 32){
      bf16x8 pa, vb[4];
      pa = *(bf16x8*)&Pt[(w*16 + lr)*PSTR + kk + lk8];
#pragma unroll
      for (int nd = 0; nd < 4; nd++) vb[nd] = *(bf16x8*)&Vtt[(nd*16 + lr)*VSTR + kk + lk8];
#pragma unroll
      for (int nd = 0; nd < 4; nd++)
        acc_o[nd] = __builtin_amdgcn_mfma_f32_16x16x32_bf16(pa, vb[nd], acc_o[nd], 0, 0, 0);
    }
  }
#pragma unroll
  for (int nd = 0; nd < 4; nd++)
#pragma unroll
    for (int r = 0; r < 4; r++){
      int ig = i0 + w*16 + ((lane >> 4) << 2) + r;
      int d = nd*16 + (lane & 15);
      Ob[(long)ig*oldd + d] = f2b(acc_o[nd][r]);
    }
}

// ---------------------------------------------------------------- bf16 transpose dst[c,r]=src[r,c]
__global__ __launch_bounds__(256) void transpose_k(
    const u16* __restrict__ src, u16* __restrict__ dst,
    int lds_, int ldd, int Hh, long sob, long soh, long dob, long doh)
{
  __shared__ u16 tile[64*72];
  int z = blockIdx.z, b_ = z / Hh, h_ = z % Hh;
  const u16* S_ = src + (long)b_*sob + (long)h_*soh;
  u16* D_ = dst + (long)b_*dob + (long)h_*doh;
  int r0 = blockIdx.y * 64, c0 = blockIdx.x * 64;
  int tid = threadIdx.x;
  for (int idx = tid; idx < 512; idx += 256){
    int r = idx >> 3, c = (idx & 7) << 3;
    *(u16x8*)&tile[r*72 + c] = *(const u16x8*)&S_[(long)(r0 + r)*lds_ + c0 + c];
  }
  __syncthreads();
  for (int idx = tid; idx < 512; idx += 256){
    int c = idx >> 3, r = (idx & 7) << 3;
    u16x8 v;
#pragma unroll
    for (int e = 0; e < 8; e++) v[e] = tile[(r + e)*72 + c];
    *(u16x8*)&D_[(long)(c0 + c)*ldd + r0 + r] = v;
  }
}

// ---------------------------------------------------------------- fp32 src -> bf16 transposed dst
__global__ __launch_bounds__(256) void transpose_cvt_k(
    const float* __restrict__ src, u16* __restrict__ dst, int lds_, int ldd)
{
  __shared__ u16 tile[64*72];
  int r0 = blockIdx.y * 64, c0 = blockIdx.x * 64;
  int tid = threadIdx.x;
  for (int idx = tid; idx < 512; idx += 256){
    int r = idx >> 3, c = (idx & 7) << 3;
    const float* s = &src[(long)(r0 + r)*lds_ + c0 + c];
#pragma unroll
    for (int e = 0; e < 8; e++) tile[r*72 + c + e] = f2b(s[e]);
  }
  __syncthreads();
  for (int idx = tid; idx < 512; idx += 256){
    int c = idx >> 3, r = (idx & 7) << 3;
    u16x8 v;
#pragma unroll
    for (int e = 0; e < 8; e++) v[e] = tile[(r + e)*72 + c];
    *(u16x8*)&dst[(long)(c0 + c)*ldd + r0 + r] = v;
  }
}

// ---------------------------------------------------------------- flat fp32 -> bf16
__global__ __launch_bounds__(256) void cvt_k(const float* __restrict__ src, u16* __restrict__ dst)
{
  long i = ((long)blockIdx.x*256 + threadIdx.x) * 4;
  float4 v = *(const float4*)&src[i];
  u16x4 o; o[0] = f2b(v.x); o[1] = f2b(v.y); o[2] = f2b(v.z); o[3] = f2b(v.w);
  *(u16x4*)&dst[i] = o;
}

// ---------------------------------------------------------------- LayerNorm row=1024, fp32 in, bf16 out
__global__ __launch_bounds__(256) void ln_k(const float* __restrict__ src, const float* __restrict__ g,
                                            const float* __restrict__ be, u16* __restrict__ out)
{
  long base = (long)blockIdx.x * 1024;
  int tid = threadIdx.x;
  const float* s = src + base + tid*4;
  float v[4] = {s[0], s[1], s[2], s[3]};
  float s1 = v[0]+v[1]+v[2]+v[3];
  float s2 = v[0]*v[0]+v[1]*v[1]+v[2]*v[2]+v[3]*v[3];
  block_red2(s1, s2);
  float mu = s1 * (1.f/1024.f);
  float var = s2 * (1.f/1024.f) - mu*mu;
  float rs = rsqrtf(var + 1e-5f);
#pragma unroll
  for (int e = 0; e < 4; e++){
    int col = tid*4 + e;
    out[base + col] = f2b((v[e]-mu)*rs*g[col] + be[col]);
  }
}

// ---------------------------------------------------------------- out = resid + LN(sum4(go) + xn + bias)  (fp32 out)
__global__ __launch_bounds__(256) void add_ln_k(const float* __restrict__ go,
    const u16* __restrict__ xn, const float* __restrict__ bias,
    const float* __restrict__ g, const float* __restrict__ be,
    const float* __restrict__ resid, float* __restrict__ outp)
{
  const long PS = 2097152;
  long base = (long)blockIdx.x * 1024;
  int tid = threadIdx.x;
  float v[4];
#pragma unroll
  for (int e = 0; e < 4; e++){
    int col = tid*4 + e;
    long idx = base + col;
    v[e] = go[idx] + go[idx + PS] + go[idx + 2*PS] + go[idx + 3*PS] + b2f(xn[idx]) + bias[col];
  }
  float s1 = v[0]+v[1]+v[2]+v[3];
  float s2 = v[0]*v[0]+v[1]*v[1]+v[2]*v[2]+v[3]*v[3];
  block_red2(s1, s2);
  float mu = s1 * (1.f/1024.f);
  float var = s2 * (1.f/1024.f) - mu*mu;
  float rs = rsqrtf(var + 1e-5f);
#pragma unroll
  for (int e = 0; e < 4; e++){
    int col = tid*4 + e;
    outp[base + col] = resid[base + col] + (v[e]-mu)*rs*g[col] + be[col];
  }
}

// ---------------------------------------------------------------- QQ = [q+u | shifted(q+v)]  (B,S,H,128)
__global__ __launch_bounds__(256) void build_qq(const u16* __restrict__ q, const float* __restrict__ u,
                                                const float* __restrict__ v, u16* __restrict__ QQ)
{
  int bi = blockIdx.x;
  long qrow = (long)bi * 1024;
  long obase = (long)bi * 2048;
  int n = bi + 2;
  int bp = n / 1025, ip = n % 1025;
  long qsrc = ip ? ((long)(bp*1024 + ip - 1)) * 1024 : -1;
  for (int t = threadIdx.x; t < 2048; t += 256){
    int h = t >> 7, e = t & 127;
    float val;
    if (e < 64) val = b2f(q[qrow + h*64 + e]) + u[h*64 + e];
    else {
      int d = e - 64;
      val = (qsrc < 0) ? 0.f : b2f(q[qsrc + h*64 + d]) + v[h*64 + d];
    }
    QQ[obase + t] = f2b(val);
  }
}

// ---------------------------------------------------------------- BB = [k | pos_emb]  (B,St,H,128)
__global__ __launch_bounds__(256) void build_bb(const u16* __restrict__ kv, const float* __restrict__ pe,
                                                u16* __restrict__ BB)
{
  int bj = blockIdx.x;
  int j = bj & 2047;
  long kvrow = (long)bj * 2048;
  long obase = (long)bj * 2048;
  for (int t = threadIdx.x; t < 2048; t += 256){
    int h = t >> 7, e = t & 127;
    u16 val = (e < 64) ? kv[kvrow + h*64 + e] : f2b(pe[(long)j*1024 + h*64 + (e - 64)]);
    BB[obase + t] = val;
  }
}

// ---------------------------------------------------------------- gelu(exact) + bias, fp32 in, bf16 out
__global__ __launch_bounds__(256) void gelu_k(const float* __restrict__ f1, const float* __restrict__ b1,
                                              u16* __restrict__ h1)
{
  long i = (long)blockIdx.x*256 + threadIdx.x;
  float x = f1[i] + b1[i & 4095];
  h1[i] = f2b(0.5f * x * (1.f + erff(x * 0.70710678118654752f)));
}

// ---------------------------------------------------------------- out3 = out2 + sum4(f2) + b2  (fp32 out)
__global__ __launch_bounds__(256) void final_k(const float* __restrict__ out2, const float* __restrict__ f2,
                                               const float* __restrict__ b2v, float* __restrict__ outp)
{
  const long PS = 2097152;
  long i = (long)blockIdx.x*256 + threadIdx.x;
  outp[i] = out2[i] + f2[i] + f2[i + PS] + f2[i + 2*PS] + f2[i + 3*PS] + b2v[i & 1023];
}

// ================================================================ host
extern "C" void kernel_launch(void* const* d_in, const int* in_sizes, int n_in,
                              void* d_out, int out_size, void* d_ws, size_t ws_size,
                              hipStream_t stream)
{
  (void)in_sizes; (void)n_in; (void)out_size; (void)ws_size;
  // B=2 S=1024 M=1024 St=2048 D=DI=1024 H=16 DH=64 DFF=4096 ; ALL inputs/output fp32
  const float* X    = (const float*)d_in[0];
  const float* ENC  = (const float*)d_in[1];
  const float* PE   = (const float*)d_in[2];
  const float* Uu   = (const float*)d_in[3];
  const float* Vv   = (const float*)d_in[4];
  const float* MEM  = (const float*)d_in[5];
  const float* WQM  = (const float*)d_in[7];
  const float* WKVM = (const float*)d_in[8];
  const float* FCWM = (const float*)d_in[9];
  const float* FCBM = (const float*)d_in[10];
  const float* LNMG = (const float*)d_in[11];
  const float* LNMB = (const float*)d_in[12];
  const float* WQC  = (const float*)d_in[13];
  const float* WKVC = (const float*)d_in[14];
  const float* FCWC = (const float*)d_in[15];
  const float* FCBC = (const float*)d_in[16];
  const float* LNCG = (const float*)d_in[17];
  const float* LNCB = (const float*)d_in[18];
  const float* W1   = (const float*)d_in[19];
  const float* B1   = (const float*)d_in[20];
  const float* W2   = (const float*)d_in[21];
  const float* B2   = (const float*)d_in[22];
  const float* LN1G = (const float*)d_in[23];
  const float* LN1B = (const float*)d_in[24];
  const float* LN2G = (const float*)d_in[25];
  const float* LN2B = (const float*)d_in[26];
  const float* LN3G = (const float*)d_in[27];
  const float* LN3B = (const float*)d_in[28];
  float* OUT = (float*)d_out;
  char* W = (char*)d_ws;
  const size_t MB = 1ull << 20;

  // ---- layout, peak 122 MB (same as R7)
  u16*   wT_a  = (u16*)(W + 0*MB);
  u16*   wT_b  = (u16*)(W + 2*MB);
  u16*   wT_c  = (u16*)(W + 6*MB);
  u16*   w1T   = (u16*)(W + 0*MB);
  u16*   xn1   = (u16*)(W + 8*MB);
  u16*   q     = (u16*)(W + 12*MB);
  u16*   o_b   = (u16*)(W + 12*MB);
  u16*   kv    = (u16*)(W + 16*MB);
  float* outb  = (float*)(W + 24*MB);
  u16*   QQ    = (u16*)(W + 32*MB);
  u16*   xn2   = (u16*)(W + 32*MB);
  u16*   qc    = (u16*)(W + 36*MB);
  u16*   BB    = (u16*)(W + 40*MB);
  u16*   kvc   = (u16*)(W + 40*MB);
  u16*   Vtc   = (u16*)(W + 48*MB);
  u16*   oc    = (u16*)(W + 52*MB);
  u16*   Vt    = (u16*)(W + 56*MB);
  u16*   w2T   = (u16*)(W + 56*MB);
  float* mzb   = (float*)(W + 64*MB);
  u16*   memb  = (u16*)(W + 68*MB);
  u16*   encb  = (u16*)(W + 68*MB);
  float* ofc   = (float*)(W + 66*MB);    // 4 partials x 8 MB
  float* f1    = (float*)(W + 66*MB);
  float* f2    = (float*)(W + 66*MB);    // 4 partials x 8 MB
  u16*   h1    = (u16*)(W + 98*MB);
  float* out2b = (float*)(W + 114*MB);

  // ================= MHA (Transformer-XL relative attention) =================
  transpose_cvt_k<<<dim3(16,16),256,0,stream>>>(WQM,  wT_a, 1024,1024);
  transpose_cvt_k<<<dim3(32,16),256,0,stream>>>(WKVM, wT_b, 2048,1024);
  transpose_cvt_k<<<dim3(16,16),256,0,stream>>>(FCWM, wT_c, 1024,1024);
  cvt_k<<<2048,256,0,stream>>>(MEM, memb);
  ln_k<<<2048,256,0,stream>>>(X, LN1G, LN1B, xn1);
  gemm_bt<2,2,true><<<dim3(8,16,1),256,0,stream>>>(xn1, wT_a, q, 1024, 1024,1024,1024, 1, 0,0,0,0,0,0);
  gemm_bt<2,2,true><<<dim3(16,8,2),256,0,stream>>>(memb, wT_b, kv, 1024, 1024,1024,2048, 1,
      1048576,0, 0,0, 4194304,0);
  gemm_bt<2,2,true><<<dim3(16,8,2),256,0,stream>>>(xn1, wT_b, kv + (size_t)1024*2048, 1024, 1024,1024,2048, 1,
      1048576,0, 0,0, 4194304,0);
  build_qq<<<2048,256,0,stream>>>(q, Uu, Vv, QQ);
  build_bb<<<4096,256,0,stream>>>(kv, PE, BB);
  transpose_k<<<dim3(1,32,32),256,0,stream>>>(kv + 1024, Vt, 2048, 2048, 16,
      4194304,64, 2097152,131072);
  attn_passA<128,true><<<dim3(32,32),256,0,stream>>>(BB, QQ, mzb, 2048, 2048, 2048,
      4194304,128, 2097152,128, 16, 0.125f, 65536);
  attn_passB<128,true><<<dim3(16,32),256,0,stream>>>(BB, QQ, Vt, mzb, o_b, 2048,
      2048,2048,2048,1024, 4194304,128, 2097152,128, 2097152,131072, 1048576,64, 16, 0.125f, 65536);
  gemm_bt<2,2,false><<<dim3(8,16,4),256,0,stream>>>(o_b, wT_c, ofc, 256, 1024,1024,1024, 4,
      0,256, 0,256, 0,2097152);
  add_ln_k<<<2048,256,0,stream>>>(ofc, xn1, FCBM, LNMG, LNMB, X, outb);

  // ================= cross attention =================
  transpose_cvt_k<<<dim3(16,16),256,0,stream>>>(WQC,  wT_a, 1024,1024);
  transpose_cvt_k<<<dim3(32,16),256,0,stream>>>(WKVC, wT_b, 2048,1024);
  transpose_cvt_k<<<dim3(16,16),256,0,stream>>>(FCWC, wT_c, 1024,1024);
  cvt_k<<<2048,256,0,stream>>>(ENC, encb);
  ln_k<<<2048,256,0,stream>>>(outb, LN2G, LN2B, xn2);
  gemm_bt<2,2,true><<<dim3(8,16,1),256,0,stream>>>(xn2, wT_a, qc, 1024, 1024,1024,1024, 1, 0,0,0,0,0,0);
  gemm_bt<2,2,true><<<dim3(16,16,1),256,0,stream>>>(encb, wT_b, kvc, 1024, 1024,1024,2048, 1, 0,0,0,0,0,0);
  transpose_k<<<dim3(1,16,32),256,0,stream>>>(kvc + 1024, Vtc, 2048, 1024, 16,
      2097152,64, 1048576,65536);
  attn_passA<64,false><<<dim3(16,32),256,0,stream>>>(kvc, qc, mzb, 1024, 2048, 1024,
      2097152,64, 1048576,64, 16, 0.125f, 32768);
  attn_passB<64,false><<<dim3(16,32),256,0,stream>>>(kvc, qc, Vtc, mzb, oc, 1024,
      2048,1024,1024,1024, 2097152,64, 1048576,64, 1048576,65536, 1048576,64, 16, 0.125f, 32768);
  gemm_bt<2,2,false><<<dim3(8,16,4),256,0,stream>>>(oc, wT_c, ofc, 256, 1024,1024,1024, 4,
      0,256, 0,256, 0,2097152);
  add_ln_k<<<2048,256,0,stream>>>(ofc, xn2, FCBC, LNCG, LNCB, outb, out2b);

  // ================= FFN =================
  transpose_cvt_k<<<dim3(64,16),256,0,stream>>>(W1, w1T, 4096,1024);
  transpose_cvt_k<<<dim3(16,64),256,0,stream>>>(W2, w2T, 1024,4096);
  ln_k<<<2048,256,0,stream>>>(out2b, LN3G, LN3B, xn2);
  gemm_bt<2,2,false><<<dim3(32,16,1),256,0,stream>>>(xn2, w1T, f1, 1024, 1024,1024,4096, 1, 0,0,0,0,0,0);
  gelu_k<<<32768,256,0,stream>>>(f1, B1, h1);
  gemm_bt<2,2,false><<<dim3(8,16,4),256,0,stream>>>(h1, w2T, f2, 1024, 4096,4096,1024, 4,
      0,1024, 0,1024, 0,2097152);
  final_k<<<8192,256,0,stream>>>(out2b, f2, B2, OUT);
}